// Round 2
// baseline (253.945 us; speedup 1.0000x reference)
//
#include <hip/hip_runtime.h>

// LNCC, separable 5-tap Gaussian (sigma=1), fused single pass.
// (N=2, C=1, D=160, H=192, W=224) fp32 -> scalar.
// R7 (resubmit; previous round failed on infra, not kernel): two H-rows per
//     thread. Same tile (32x16x20) and grid (1344 blocks), block 640->320.
//     H-blur reads 6 wb rows per 2 outputs (was 10 per 1 output across 2
//     threads) -> ~40% fewer LDS reads in the dominant stage; per-output
//     loop/addressing VALU halved. 4 blocks/CU resident (LDS 37KB),
//     block rounds 5.25/4 = 1.31 (was 1.75).

#define NB 2
#define DD 160
#define HH 192
#define WW 224
#define SH 224
#define SD (224*192)
#define SN (224*192*160)

#define TW 32
#define TH 16
#define ROWS (TH+4)          // 20 staged rows
#define DCHUNK 20
#define NCHUNK (DD/DCHUNK)   // 8

#define K0 0.05448868f
#define K1 0.24420134f
#define K2 0.40261995f

__global__ __launch_bounds__(320) void lncc_main(
    const float* __restrict__ A, const float* __restrict__ B,
    const float* __restrict__ M, double* __restrict__ acc)
{
    __shared__ float2 sIJ[2][ROWS][36];   // raw (I,J) + W halo, dbuf
    __shared__ float4 wbA[2][ROWS][32];   // (bI,bII,bJ,bJJ), dbuf
    __shared__ float  wbC[2][ROWS][32];   // bIJ, dbuf
    __shared__ float  redL[5], redM[5];

    const int wt = blockIdx.x;           // 0..6
    const int ht = blockIdx.y;           // 0..11
    const int zz = blockIdx.z;           // 0..15
    const int n  = zz >> 3;
    const int dc = zz & 7;
    const int w0 = wt * TW, h0 = ht * TH, d0 = dc * DCHUNK;

    const float* __restrict__ Ai = A + (size_t)n * SN;
    const float* __restrict__ Bi = B + (size_t)n * SN;
    const float* __restrict__ Mi = M + (size_t)n * SN;

    const int tid = threadIdx.x;
    const int rh  = tid >> 5;            // 0..9  (row-pair index)
    const int c   = tid & 31;            // 0..31
    const int ra  = rh * 2;              // staged rows ra, ra+1
    const int rb  = ra + 1;

    // ---- per-row global addressing (rows a and b) ----
    const int gha = h0 + ra - 2;
    const int ghb = gha + 1;
    const bool hva = (unsigned)gha < (unsigned)HH;
    const bool hvb = (unsigned)ghb < (unsigned)HH;
    const int ghca = hva ? gha : 0;
    const int ghcb = hvb ? ghb : 0;
    const int hwma = ghca * SH + (w0 + c);
    const int hwmb = ghcb * SH + (w0 + c);

    const int gwl = w0 + c - 2, gwr = w0 + c + 2;
    const bool lc = (c < 2)   && (gwl >= 0);
    const bool rc = (c >= 30) && (gwr < WW);
    const int  whx = lc ? gwl : (rc ? gwr : 0);
    const bool anyc  = lc || rc;
    const bool anyha = anyc && hva;
    const bool anyhb = anyc && hvb;
    const int hwha = ghca * SH + whx;
    const int hwhb = ghcb * SH + whx;

    const int mbasea = (h0 + ra) * SH + (w0 + c);
    const int mbaseb = mbasea + SH;
    const bool orow  = (rh < 8);         // output row-pair threads

    // D-direction shift registers, rows a and b (oldest..newest)
    float pI0a=0.f,pI1a=0.f,pI2a=0.f,pI3a=0.f;
    float pJ0a=0.f,pJ1a=0.f,pJ2a=0.f,pJ3a=0.f;
    float pC0a=0.f,pC1a=0.f,pC2a=0.f,pC3a=0.f;
    float pS0a=0.f,pS1a=0.f,pS2a=0.f,pS3a=0.f;
    float pT0a=0.f,pT1a=0.f,pT2a=0.f,pT3a=0.f;
    float pI0b=0.f,pI1b=0.f,pI2b=0.f,pI3b=0.f;
    float pJ0b=0.f,pJ1b=0.f,pJ2b=0.f,pJ3b=0.f;
    float pC0b=0.f,pC1b=0.f,pC2b=0.f,pC3b=0.f;
    float pS0b=0.f,pS1b=0.f,pS2b=0.f,pS3b=0.f;
    float pT0b=0.f,pT1b=0.f,pT2b=0.f,pT3b=0.f;
    float accL = 0.f, accM = 0.f;

    // prefetch registers for the slice staged at iteration k
    float nIa=0.f,nJa=0.f,nIb=0.f,nJb=0.f;
    float nHIa=0.f,nHJa=0.f,nHIb=0.f,nHJb=0.f;
    {
        const int dd = d0 - 2;
        if (dd >= 0) {
            const int dof = dd * SD;
            if (hva)  { nIa  = Ai[dof + hwma]; nJa  = Bi[dof + hwma]; }
            if (hvb)  { nIb  = Ai[dof + hwmb]; nJb  = Bi[dof + hwmb]; }
            if (anyha){ nHIa = Ai[dof + hwha]; nHJa = Bi[dof + hwha]; }
            if (anyhb){ nHIb = Ai[dof + hwhb]; nHJb = Bi[dof + hwhb]; }
        }
    }

    const int NIT = DCHUNK + 6;          // 26
    for (int k = 0; k < NIT; ++k) {
        const int pw = k & 1;            // parity staged THIS iter
        const int px = pw ^ 1;

        // ---- W: stage prefetched raw slice (rows a and b) ----
        if (k < DCHUNK + 4) {
            sIJ[pw][ra][c + 2] = make_float2(nIa, nJa);
            sIJ[pw][rb][c + 2] = make_float2(nIb, nJb);
            if (c < 2) {
                sIJ[pw][ra][c] = make_float2(nHIa, nHJa);
                sIJ[pw][rb][c] = make_float2(nHIb, nHJb);
            } else if (c >= 30) {
                sIJ[pw][ra][c + 4] = make_float2(nHIa, nHJa);
                sIJ[pw][rb][c + 4] = make_float2(nHIb, nHJb);
            }
        }

        // ---- prefetch slice k+1 ----
        nIa=nJa=nIb=nJb=nHIa=nHJa=nHIb=nHJb=0.f;
        {
            const int dd = d0 - 1 + k;
            if ((k + 1 < DCHUNK + 4) && (dd >= 0) && (dd < DD)) {
                const int dof = dd * SD;
                if (hva)  { nIa  = Ai[dof + hwma]; nJa  = Bi[dof + hwma]; }
                if (hvb)  { nIb  = Ai[dof + hwmb]; nJb  = Bi[dof + hwmb]; }
                if (anyha){ nHIa = Ai[dof + hwha]; nHJa = Bi[dof + hwha]; }
                if (anyhb){ nHIb = Ai[dof + hwhb]; nHJb = Bi[dof + hwhb]; }
            }
        }

        // ---- this iteration's mask values ----
        const int  dout = d0 - 6 + k;
        const bool outv = (k >= 6) && orow;
        float mvala = 0.f, mvalb = 0.f;
        if (outv) {
            mvala = Mi[dout * SD + mbasea];
            mvalb = Mi[dout * SD + mbaseb];
        }

        // ---- X: W-blur of slice staged last iteration (rows a and b) ----
        if (k >= 1 && k <= DCHUNK + 4) {
            {
                const float2 v0 = sIJ[px][ra][c];
                const float2 v1 = sIJ[px][ra][c + 1];
                const float2 v2 = sIJ[px][ra][c + 2];
                const float2 v3 = sIJ[px][ra][c + 3];
                const float2 v4 = sIJ[px][ra][c + 4];
                const float bi  = K0*(v0.x+v4.x) + K1*(v1.x+v3.x) + K2*v2.x;
                const float bj  = K0*(v0.y+v4.y) + K1*(v1.y+v3.y) + K2*v2.y;
                const float bij = K0*(v0.x*v0.y+v4.x*v4.y) + K1*(v1.x*v1.y+v3.x*v3.y) + K2*v2.x*v2.y;
                const float bii = K0*(v0.x*v0.x+v4.x*v4.x) + K1*(v1.x*v1.x+v3.x*v3.x) + K2*v2.x*v2.x;
                const float bjj = K0*(v0.y*v0.y+v4.y*v4.y) + K1*(v1.y*v1.y+v3.y*v3.y) + K2*v2.y*v2.y;
                wbA[px][ra][c] = make_float4(bi, bii, bj, bjj);
                wbC[px][ra][c] = bij;
            }
            {
                const float2 v0 = sIJ[px][rb][c];
                const float2 v1 = sIJ[px][rb][c + 1];
                const float2 v2 = sIJ[px][rb][c + 2];
                const float2 v3 = sIJ[px][rb][c + 3];
                const float2 v4 = sIJ[px][rb][c + 4];
                const float bi  = K0*(v0.x+v4.x) + K1*(v1.x+v3.x) + K2*v2.x;
                const float bj  = K0*(v0.y+v4.y) + K1*(v1.y+v3.y) + K2*v2.y;
                const float bij = K0*(v0.x*v0.y+v4.x*v4.y) + K1*(v1.x*v1.y+v3.x*v3.y) + K2*v2.x*v2.y;
                const float bii = K0*(v0.x*v0.x+v4.x*v4.x) + K1*(v1.x*v1.x+v3.x*v3.x) + K2*v2.x*v2.x;
                const float bjj = K0*(v0.y*v0.y+v4.y*v4.y) + K1*(v1.y*v1.y+v3.y*v3.y) + K2*v2.y*v2.y;
                wbA[px][rb][c] = make_float4(bi, bii, bj, bjj);
                wbC[px][rb][c] = bij;
            }
        }

        // ---- Y: H-blur (6 rows -> 2 outputs) + D-pipeline ----
        if (k >= 2 && orow) {
            const float4 q0 = wbA[pw][ra    ][c];
            const float4 q1 = wbA[pw][ra + 1][c];
            const float4 q2 = wbA[pw][ra + 2][c];
            const float4 q3 = wbA[pw][ra + 3][c];
            const float4 q4 = wbA[pw][ra + 4][c];
            const float4 q5 = wbA[pw][ra + 5][c];
            const float e0 = wbC[pw][ra    ][c];
            const float e1 = wbC[pw][ra + 1][c];
            const float e2 = wbC[pw][ra + 2][c];
            const float e3 = wbC[pw][ra + 3][c];
            const float e4 = wbC[pw][ra + 4][c];
            const float e5 = wbC[pw][ra + 5][c];

            const float hIa  = K0*(q0.x+q4.x) + K1*(q1.x+q3.x) + K2*q2.x;
            const float hIIa = K0*(q0.y+q4.y) + K1*(q1.y+q3.y) + K2*q2.y;
            const float hJa  = K0*(q0.z+q4.z) + K1*(q1.z+q3.z) + K2*q2.z;
            const float hJJa = K0*(q0.w+q4.w) + K1*(q1.w+q3.w) + K2*q2.w;
            const float hIJa = K0*(e0+e4)     + K1*(e1+e3)     + K2*e2;

            const float hIb  = K0*(q1.x+q5.x) + K1*(q2.x+q4.x) + K2*q3.x;
            const float hIIb = K0*(q1.y+q5.y) + K1*(q2.y+q4.y) + K2*q3.y;
            const float hJb  = K0*(q1.z+q5.z) + K1*(q2.z+q4.z) + K2*q3.z;
            const float hJJb = K0*(q1.w+q5.w) + K1*(q2.w+q4.w) + K2*q3.w;
            const float hIJb = K0*(e1+e5)     + K1*(e2+e4)     + K2*e3;

            if (outv) {
                {
                    const float bI  = K0*(pI0a+hIa)  + K1*(pI1a+pI3a) + K2*pI2a;
                    const float bJ  = K0*(pJ0a+hJa)  + K1*(pJ1a+pJ3a) + K2*pJ2a;
                    const float bIJ = K0*(pC0a+hIJa) + K1*(pC1a+pC3a) + K2*pC2a;
                    const float bII = K0*(pS0a+hIIa) + K1*(pS1a+pS3a) + K2*pS2a;
                    const float bJJ = K0*(pT0a+hJJa) + K1*(pT1a+pT3a) + K2*pT2a;
                    const float cross = bIJ - bI * bJ;
                    const float vI = fmaxf(bII - bI * bI, 0.f) + 1e-5f;
                    const float vJ = fmaxf(bJJ - bJ * bJ, 0.f) + 1e-5f;
                    const float lncc = 1.0f - cross * rsqrtf(vI * vJ);
                    accL += lncc * mvala;
                    accM += mvala;
                }
                {
                    const float bI  = K0*(pI0b+hIb)  + K1*(pI1b+pI3b) + K2*pI2b;
                    const float bJ  = K0*(pJ0b+hJb)  + K1*(pJ1b+pJ3b) + K2*pJ2b;
                    const float bIJ = K0*(pC0b+hIJb) + K1*(pC1b+pC3b) + K2*pC2b;
                    const float bII = K0*(pS0b+hIIb) + K1*(pS1b+pS3b) + K2*pS2b;
                    const float bJJ = K0*(pT0b+hJJb) + K1*(pT1b+pT3b) + K2*pT2b;
                    const float cross = bIJ - bI * bJ;
                    const float vI = fmaxf(bII - bI * bI, 0.f) + 1e-5f;
                    const float vJ = fmaxf(bJJ - bJ * bJ, 0.f) + 1e-5f;
                    const float lncc = 1.0f - cross * rsqrtf(vI * vJ);
                    accL += lncc * mvalb;
                    accM += mvalb;
                }
            }

            pI0a=pI1a; pI1a=pI2a; pI2a=pI3a; pI3a=hIa;
            pJ0a=pJ1a; pJ1a=pJ2a; pJ2a=pJ3a; pJ3a=hJa;
            pC0a=pC1a; pC1a=pC2a; pC2a=pC3a; pC3a=hIJa;
            pS0a=pS1a; pS1a=pS2a; pS2a=pS3a; pS3a=hIIa;
            pT0a=pT1a; pT1a=pT2a; pT2a=pT3a; pT3a=hJJa;
            pI0b=pI1b; pI1b=pI2b; pI2b=pI3b; pI3b=hIb;
            pJ0b=pJ1b; pJ1b=pJ2b; pJ2b=pJ3b; pJ3b=hJb;
            pC0b=pC1b; pC1b=pC2b; pC2b=pC3b; pC3b=hIJb;
            pS0b=pS1b; pS1b=pS2b; pS2b=pS3b; pS3b=hIIb;
            pT0b=pT1b; pT1b=pT2b; pT2b=pT3b; pT3b=hJJb;
        }

        __syncthreads();
    }

    // ---- reduction (5 waves) ----
#pragma unroll
    for (int off = 32; off > 0; off >>= 1) {
        accL += __shfl_down(accL, off, 64);
        accM += __shfl_down(accM, off, 64);
    }
    const int wave = tid >> 6;
    if ((tid & 63) == 0) { redL[wave] = accL; redM[wave] = accM; }
    __syncthreads();
    if (tid == 0) {
        float sL = 0.f, sM = 0.f;
#pragma unroll
        for (int kk = 0; kk < 5; ++kk) { sL += redL[kk]; sM += redM[kk]; }
        atomicAdd(&acc[0], (double)sL);
        atomicAdd(&acc[1], (double)sM);
    }
}

__global__ void lncc_final(const double* __restrict__ acc, float* __restrict__ out)
{
    out[0] = (float)(acc[0] / (acc[1] + 1e-8));
}

extern "C" void kernel_launch(void* const* d_in, const int* in_sizes, int n_in,
                              void* d_out, int out_size, void* d_ws, size_t ws_size,
                              hipStream_t stream)
{
    const float* A = (const float*)d_in[0];
    const float* B = (const float*)d_in[1];
    const float* M = (const float*)d_in[2];
    double* acc = (double*)d_ws;

    hipMemsetAsync(d_ws, 0, 2 * sizeof(double), stream);

    dim3 grid(WW / TW, HH / TH, NB * NCHUNK);   // (7, 12, 16) = 1344 blocks
    dim3 block(320);
    hipLaunchKernelGGL(lncc_main, grid, block, 0, stream, A, B, M, acc);
    hipLaunchKernelGGL(lncc_final, dim3(1), dim3(1), 0, stream, acc, (float*)d_out);
}

// Round 3
// 229.366 us; speedup vs baseline: 1.1072x; 1.1072x over previous
//
#include <hip/hip_runtime.h>

// LNCC, separable 5-tap Gaussian (sigma=1), fused single pass.
// (N=2, C=1, D=160, H=192, W=224) fp32 -> scalar.
// R8: R6 structure (640 thr, 32x16x20 tile, 1 row/thread — R7's 2-row variant
//     regressed via occupancy loss) + packed-fp32 math: all (I,J)-symmetric
//     blur chains written as ext_vector float2 so the backend emits
//     v_pk_fma_f32/v_pk_add_f32 (full-rate on gfx950). wbA reordered to
//     (bI,bJ,bII,bJJ) so .xy/.zw are the packed lanes. ~35-40% fewer VALU
//     instructions; VALU-issue time was the 85 us invariant across R6/R7.

#define NB 2
#define DD 160
#define HH 192
#define WW 224
#define SH 224
#define SD (224*192)
#define SN (224*192*160)

#define TW 32
#define TH 16
#define ROWS (TH+4)          // 20
#define DCHUNK 20
#define NCHUNK (DD/DCHUNK)   // 8

#define K0 0.05448868f
#define K1 0.24420134f
#define K2 0.40261995f

typedef float v2f __attribute__((ext_vector_type(2)));
typedef float v4f __attribute__((ext_vector_type(4)));

__global__ __launch_bounds__(640) void lncc_main(
    const float* __restrict__ A, const float* __restrict__ B,
    const float* __restrict__ M, double* __restrict__ acc)
{
    __shared__ v2f  sIJ[2][ROWS][36];   // raw (I,J) + W halo, dbuf
    __shared__ v4f  wbA[2][ROWS][32];   // (bI,bJ,bII,bJJ), dbuf
    __shared__ float wbC[2][ROWS][32];  // bIJ, dbuf
    __shared__ float redL[10], redM[10];

    const int wt = blockIdx.x;           // 0..6
    const int ht = blockIdx.y;           // 0..11
    const int zz = blockIdx.z;           // 0..15
    const int n  = zz >> 3;
    const int dc = zz & 7;
    const int w0 = wt * TW, h0 = ht * TH, d0 = dc * DCHUNK;

    const float* __restrict__ Ai = A + (size_t)n * SN;
    const float* __restrict__ Bi = B + (size_t)n * SN;
    const float* __restrict__ Mi = M + (size_t)n * SN;

    const int tid = threadIdx.x;
    const int r   = tid >> 5;            // 0..19
    const int c   = tid & 31;            // 0..31

    const int gh  = h0 + r - 2;
    const bool hv = (unsigned)gh < (unsigned)HH;
    const int ghc = hv ? gh : 0;
    const int hwm = ghc * SH + (w0 + c);          // 32-bit offsets
    const int gwl = w0 + c - 2, gwr = w0 + c + 2;
    const bool lv = hv && (c < 2)   && (gwl >= 0);
    const bool rv = hv && (c >= 30) && (gwr < WW);
    const bool anyh = lv || rv;
    const int hwh = ghc * SH + (lv ? gwl : (rv ? gwr : 0));
    const int mbase = (h0 + r) * SH + (w0 + c);

    // D-direction shift-register pipelines (oldest..newest)
    v2f pP0 = 0.f, pP1 = 0.f, pP2 = 0.f, pP3 = 0.f;   // (bI,bJ)
    v2f pQ0 = 0.f, pQ1 = 0.f, pQ2 = 0.f, pQ3 = 0.f;   // (bII,bJJ)
    float pC0 = 0.f, pC1 = 0.f, pC2 = 0.f, pC3 = 0.f; // bIJ
    float accL = 0.f, accM = 0.f;

    // prefetch registers for the slice staged at iteration k
    v2f nM = 0.f, nH = 0.f;
    {
        const int dd = d0 - 2;
        if (dd >= 0) {
            const int dof = dd * SD;
            if (hv)   { nM.x = Ai[dof + hwm]; nM.y = Bi[dof + hwm]; }
            if (anyh) { nH.x = Ai[dof + hwh]; nH.y = Bi[dof + hwh]; }
        }
    }

    const int NIT = DCHUNK + 6;          // 26
#pragma unroll 2
    for (int k = 0; k < NIT; ++k) {
        const int pw = k & 1;            // parity staged THIS iter
        const int px = pw ^ 1;

        // ---- W: stage prefetched raw slice (slices d0-2 .. d0+DCHUNK+1) ----
        if (k < DCHUNK + 4) {
            sIJ[pw][r][c + 2] = nM;
            if (c < 2)        sIJ[pw][r][c]     = nH;
            else if (c >= 30) sIJ[pw][r][c + 4] = nH;
        }

        // ---- prefetch slice k+1 ----
        nM = 0.f; nH = 0.f;
        {
            const int dd = d0 - 1 + k;
            if ((k + 1 < DCHUNK + 4) && (dd >= 0) && (dd < DD)) {
                const int dof = dd * SD;
                if (hv)   { nM.x = Ai[dof + hwm]; nM.y = Bi[dof + hwm]; }
                if (anyh) { nH.x = Ai[dof + hwh]; nH.y = Bi[dof + hwh]; }
            }
        }
        // ---- this iteration's mask value ----
        const int  dout = d0 - 6 + k;
        const bool outv = (k >= 6) && (r < TH);
        float mval = 0.f;
        if (outv) mval = Mi[dout * SD + mbase];

        // ---- X: W-blur of slice staged last iteration (packed I/J) ----
        if (k >= 1 && k <= DCHUNK + 4) {
            const v2f v0 = sIJ[px][r][c];
            const v2f v1 = sIJ[px][r][c + 1];
            const v2f v2 = sIJ[px][r][c + 2];
            const v2f v3 = sIJ[px][r][c + 3];
            const v2f v4 = sIJ[px][r][c + 4];
            const v2f b  = K0*(v0+v4) + K1*(v1+v3) + K2*v2;           // (bI,bJ)
            const v2f bs = K0*(v0*v0+v4*v4) + K1*(v1*v1+v3*v3) + K2*(v2*v2); // (bII,bJJ)
            const float bij = K0*(v0.x*v0.y+v4.x*v4.y) + K1*(v1.x*v1.y+v3.x*v3.y) + K2*(v2.x*v2.y);
            wbA[px][r][c] = (v4f){b.x, b.y, bs.x, bs.y};
            wbC[px][r][c] = bij;
        }

        // ---- Y: H-blur of slice staged two iters ago + D-pipeline ----
        if (k >= 2 && r < TH) {
            const v4f a0 = wbA[pw][r][c];
            const v4f a1 = wbA[pw][r + 1][c];
            const v4f a2 = wbA[pw][r + 2][c];
            const v4f a3 = wbA[pw][r + 3][c];
            const v4f a4 = wbA[pw][r + 4][c];
            const float c0 = wbC[pw][r][c];
            const float c1 = wbC[pw][r + 1][c];
            const float c2 = wbC[pw][r + 2][c];
            const float c3 = wbC[pw][r + 3][c];
            const float c4 = wbC[pw][r + 4][c];
            const v2f h1 = K0*(a0.xy+a4.xy) + K1*(a1.xy+a3.xy) + K2*a2.xy; // (hI,hJ)
            const v2f h2 = K0*(a0.zw+a4.zw) + K1*(a1.zw+a3.zw) + K2*a2.zw; // (hII,hJJ)
            const float hc = K0*(c0+c4) + K1*(c1+c3) + K2*c2;

            if (outv) {
                const v2f bP = K0*(pP0+h1) + K1*(pP1+pP3) + K2*pP2;   // (bI,bJ)
                const v2f bS = K0*(pQ0+h2) + K1*(pQ1+pQ3) + K2*pQ2;   // (bII,bJJ)
                const float bC = K0*(pC0+hc) + K1*(pC1+pC3) + K2*pC2; // bIJ
                const float cross = bC - bP.x * bP.y;
                const float vI = fmaxf(bS.x - bP.x * bP.x, 0.f) + 1e-5f;
                const float vJ = fmaxf(bS.y - bP.y * bP.y, 0.f) + 1e-5f;
                const float lncc = 1.0f - cross * rsqrtf(vI * vJ);
                accL += lncc * mval;
                accM += mval;
            }

            pP0 = pP1; pP1 = pP2; pP2 = pP3; pP3 = h1;
            pQ0 = pQ1; pQ1 = pQ2; pQ2 = pQ3; pQ3 = h2;
            pC0 = pC1; pC1 = pC2; pC2 = pC3; pC3 = hc;
        }

        __syncthreads();
    }

    // ---- reduction ----
#pragma unroll
    for (int off = 32; off > 0; off >>= 1) {
        accL += __shfl_down(accL, off, 64);
        accM += __shfl_down(accM, off, 64);
    }
    const int wave = tid >> 6;
    if ((tid & 63) == 0) { redL[wave] = accL; redM[wave] = accM; }
    __syncthreads();
    if (tid == 0) {
        float sL = 0.f, sM = 0.f;
#pragma unroll
        for (int kk = 0; kk < 10; ++kk) { sL += redL[kk]; sM += redM[kk]; }
        atomicAdd(&acc[0], (double)sL);
        atomicAdd(&acc[1], (double)sM);
    }
}

__global__ void lncc_final(const double* __restrict__ acc, float* __restrict__ out)
{
    out[0] = (float)(acc[0] / (acc[1] + 1e-8));
}

extern "C" void kernel_launch(void* const* d_in, const int* in_sizes, int n_in,
                              void* d_out, int out_size, void* d_ws, size_t ws_size,
                              hipStream_t stream)
{
    const float* A = (const float*)d_in[0];
    const float* B = (const float*)d_in[1];
    const float* M = (const float*)d_in[2];
    double* acc = (double*)d_ws;

    hipMemsetAsync(d_ws, 0, 2 * sizeof(double), stream);

    dim3 grid(WW / TW, HH / TH, NB * NCHUNK);   // (7, 12, 16) = 1344 blocks
    dim3 block(640);
    hipLaunchKernelGGL(lncc_main, grid, block, 0, stream, A, B, M, acc);
    hipLaunchKernelGGL(lncc_final, dim3(1), dim3(1), 0, stream, acc, (float*)d_out);
}